// Round 11
// baseline (840.686 us; speedup 1.0000x reference)
//
#include <hip/hip_runtime.h>
#include <hip/hip_bf16.h>

#define N_NODES 100000
#define N_PAD   100032   // 1563 * 64, padding for guard-free MFMA
#define N_EDGES 1200000
#define HID 64
#define OUT_DIM 112
#define NLAYERS 7

static constexpr int SCAN_BLOCKS = (N_NODES + 255) / 256;  // 391

typedef __attribute__((ext_vector_type(8))) short short8v;
typedef __attribute__((ext_vector_type(4))) float f32x4;
typedef unsigned int uint;
typedef unsigned short ushort;
typedef __attribute__((ext_vector_type(4))) uint uintx4;   // for nontemporal builtins

__device__ __forceinline__ unsigned f2b(float f) {
    unsigned u = __builtin_bit_cast(unsigned, f);
    return (u + 0x7FFFu + ((u >> 16) & 1u)) >> 16;   // RNE bf16 bits in low 16
}
__device__ __forceinline__ float blo(uint v) {
    return __builtin_bit_cast(float, (v & 0xFFFFu) << 16);
}
__device__ __forceinline__ float bhi(uint v) {
    return __builtin_bit_cast(float, v & 0xFFFF0000u);
}

// ---------------- CSR build (rank-based, no scatter kernel) ----------------

// one atomic pass: final counts in cnt AND per-dst rank per edge (coalesced write)
__global__ __launch_bounds__(256) void k_rank(const int* __restrict__ dst, int* __restrict__ cnt,
                                              int* __restrict__ rank) {
    int e0 = (blockIdx.x * 256 + threadIdx.x) * 4;
    if (e0 + 3 < N_EDGES) {
        int4 d4 = *(const int4*)&dst[e0];
        int r0 = atomicAdd(&cnt[d4.x], 1);
        int r1 = atomicAdd(&cnt[d4.y], 1);
        int r2 = atomicAdd(&cnt[d4.z], 1);
        int r3 = atomicAdd(&cnt[d4.w], 1);
        *(int4*)&rank[e0] = make_int4(r0, r1, r2, r3);
    } else {
        for (int e = e0; e < N_EDGES; ++e) rank[e] = atomicAdd(&cnt[dst[e]], 1);
    }
}

__global__ __launch_bounds__(256) void k_scan_a(const int* __restrict__ cnt, int* __restrict__ inc,
                                                int* __restrict__ bsum) {
    __shared__ int lds[4];
    int i = blockIdx.x * 256 + threadIdx.x;
    int v = (i < N_NODES) ? cnt[i] : 0;
    int lane = threadIdx.x & 63, w = threadIdx.x >> 6;
    #pragma unroll
    for (int d = 1; d < 64; d <<= 1) {
        int u = __shfl_up(v, d, 64);
        if (lane >= d) v += u;
    }
    if (lane == 63) lds[w] = v;
    __syncthreads();
    int add = 0;
    for (int j = 0; j < w; ++j) add += lds[j];
    v += add;
    if (i < N_NODES) inc[i] = v;
    if (threadIdx.x == 255) bsum[blockIdx.x] = v;
}

__global__ __launch_bounds__(512) void k_scan_b(const int* __restrict__ bsum, int* __restrict__ boff, int nb) {
    __shared__ int lds[8];
    int t = threadIdx.x;
    int v0 = (t < nb) ? bsum[t] : 0;
    int v = v0;
    int lane = t & 63, w = t >> 6;
    #pragma unroll
    for (int d = 1; d < 64; d <<= 1) {
        int u = __shfl_up(v, d, 64);
        if (lane >= d) v += u;
    }
    if (lane == 63) lds[w] = v;
    __syncthreads();
    int add = 0;
    for (int j = 0; j < w; ++j) add += lds[j];
    boff[t] = v + add - v0;  // exclusive prefix
}

__global__ __launch_bounds__(256) void k_scan_c(const int* __restrict__ inc, const int* __restrict__ boff,
                                                int* __restrict__ rp) {
    int i = blockIdx.x * 256 + threadIdx.x;
    if (i < N_NODES) {
        rp[i + 1] = inc[i] + boff[blockIdx.x];
        if (i == 0) rp[0] = 0;
    }
}

// ---------------- weight prep: transpose + bf16 ----------------
// W1T[l][o][k] (128x64), W2T[l][o][k] (64x128), WnT[o][k] (64x128), WoT[o][k] (112x64)
__global__ __launch_bounds__(256) void k_prep_w(const float* __restrict__ W1, const float* __restrict__ W2,
                                                const float* __restrict__ Wn, const float* __restrict__ Wo,
                                                short* __restrict__ W1T, short* __restrict__ W2T,
                                                short* __restrict__ WnT, short* __restrict__ WoT) {
    int t = blockIdx.x * 256 + threadIdx.x;
    if (t < NLAYERS * 8192) {
        int l = t >> 13, r = t & 8191;
        int o1 = r >> 6, k1 = r & 63;
        W1T[t] = (short)f2b(W1[l * 8192 + k1 * 128 + o1]);
        int o2 = r >> 7, k2 = r & 127;
        W2T[t] = (short)f2b(W2[l * 8192 + k2 * 64 + o2]);
        if (t < 8192) {
            int o = t >> 7, k = t & 127;
            WnT[t] = (short)f2b(Wn[k * 64 + o]);
        }
        if (t < OUT_DIM * 64) {
            int o = t >> 6, k = t & 63;
            WoT[t] = (short)f2b(Wo[k * OUT_DIM + o]);
        }
    }
}

// ---------------- encoders / permute ----------------

// MFMA node encoder: h = nf@Wn + bn; xb = bf16(relu(LN0(h))).
__global__ __launch_bounds__(256) void k_node_enc_mfma(
    const float* __restrict__ nf, const short* __restrict__ WnT, const float* __restrict__ bn,
    const float* __restrict__ g, const float* __restrict__ b,
    float* __restrict__ h, ushort* __restrict__ xb) {
    __shared__ __align__(16) short Wns[8192];      // [o=64][k=128], XOR-swizzled
    __shared__ __align__(16) short nfs[4][2048];   // per-wave [node=16][k=128]
    int tid = threadIdx.x, lane = tid & 63, w = tid >> 6;

    {
        const int4* gp = (const int4*)WnT;
        for (int u = tid; u < 1024; u += 256) {
            int byte = u * 16;
            int off = byte ^ (((byte >> 8) & 7) << 4);   // rows = 256B
            *(int4*)((char*)Wns + off) = gp[u];
        }
    }
    int nbase = blockIdx.x * 64 + w * 16;
    #pragma unroll
    for (int it = 0; it < 8; ++it) {
        int idx = it * 256 + lane * 4;       // [16][128] f32 elems
        int node = idx >> 7, k0 = idx & 127;
        int gn = nbase + node;
        float4 v = (gn < N_NODES) ? *(const float4*)&nf[(size_t)gn * 128 + k0]
                                  : make_float4(0.f, 0.f, 0.f, 0.f);
        uint2 pk;
        pk.x = f2b(v.x) | (f2b(v.y) << 16);
        pk.y = f2b(v.z) | (f2b(v.w) << 16);
        int boff = (node * 256 + k0 * 2) ^ ((node & 7) << 4);
        *(uint2*)((char*)nfs[w] + boff) = pk;
    }
    __syncthreads();

    int cg = lane >> 4, cl = lane & 15;
    float bv[4], gv[4], bbv[4];
    #pragma unroll
    for (int t = 0; t < 4; ++t) {
        bv[t] = bn[t * 16 + cl]; gv[t] = g[t * 16 + cl]; bbv[t] = b[t * 16 + cl];
    }
    f32x4 c[4];
    #pragma unroll
    for (int t = 0; t < 4; ++t) c[t] = (f32x4){bv[t], bv[t], bv[t], bv[t]};
    #pragma unroll
    for (int s = 0; s < 4; ++s) {
        int aoff = (cl * 256 + s * 64 + cg * 16) ^ ((cl & 7) << 4);
        short8v af = *(const short8v*)((char*)nfs[w] + aoff);
        #pragma unroll
        for (int t = 0; t < 4; ++t) {
            int o = t * 16 + cl;
            int boff = (o * 256 + s * 64 + cg * 16) ^ ((o & 7) << 4);
            short8v bfv = *(const short8v*)((char*)Wns + boff);
            c[t] = __builtin_amdgcn_mfma_f32_16x16x32_bf16(af, bfv, c[t], 0, 0, 0);
        }
    }
    float s2[4] = {0, 0, 0, 0}, q2[4] = {0, 0, 0, 0};
    #pragma unroll
    for (int t = 0; t < 4; ++t)
        #pragma unroll
        for (int r = 0; r < 4; ++r) {
            int node = nbase + cg * 4 + r, o = t * 16 + cl;
            h[(size_t)node * 64 + o] = c[t][r];
            s2[r] += c[t][r]; q2[r] += c[t][r] * c[t][r];
        }
    #pragma unroll
    for (int r = 0; r < 4; ++r)
        #pragma unroll
        for (int d = 1; d < 16; d <<= 1) {
            s2[r] += __shfl_xor(s2[r], d, 16);
            q2[r] += __shfl_xor(q2[r], d, 16);
        }
    #pragma unroll
    for (int r = 0; r < 4; ++r) {
        float mu = s2[r] * (1.f / 64.f);
        float var = q2[r] * (1.f / 64.f) - mu * mu;
        float rv = rsqrtf(var + 1e-5f);
        #pragma unroll
        for (int t = 0; t < 4; ++t) {
            int node = nbase + cg * 4 + r, o = t * 16 + cl;
            float xv = fmaxf((c[t][r] - mu) * rv * gv[t] + bbv[t], 0.f);
            xb[(size_t)node * 64 + o] = (ushort)f2b(xv);
        }
    }
}

// permute edges into dst-sorted order: efb[p] = bf16(ef[e]) (16B row), ssrc[p] = src[e].
// coalesced reads, scattered NT writes (24B payload/edge vs old 132B).
__global__ __launch_bounds__(256) void k_perm(
    const float* __restrict__ ef, const int* __restrict__ dst, const int* __restrict__ rank,
    const int* __restrict__ rp, const int* __restrict__ src,
    int* __restrict__ ssrc, ushort* __restrict__ efb) {
    int e0 = (blockIdx.x * 256 + threadIdx.x) * 2;
    #pragma unroll
    for (int u = 0; u < 2; ++u) {
        int e = e0 + u;
        if (e < N_EDGES) {
            int p = rp[dst[e]] + rank[e];
            __builtin_nontemporal_store(src[e], &ssrc[p]);
            float4 a = *(const float4*)&ef[(size_t)e * 8];
            float4 b = *(const float4*)&ef[(size_t)e * 8 + 4];
            uintx4 pk;
            pk[0] = f2b(a.x) | (f2b(a.y) << 16);
            pk[1] = f2b(a.z) | (f2b(a.w) << 16);
            pk[2] = f2b(b.x) | (f2b(b.y) << 16);
            pk[3] = f2b(b.z) | (f2b(b.w) << 16);
            __builtin_nontemporal_store(pk, (uintx4*)&efb[(size_t)p * 8]);
        }
    }
}

// ---------------- per-layer kernels ----------------

// aggregation with ON-THE-FLY edge encoding (eh = ef@We + be recomputed per edge:
// 64 FMA/lane vs re-streaming 128B/edge -> trades cheap VALU for 144 MB/layer of HBM).
// No max-subtraction (logits bounded ~9 -> exp safe in f32; T/S == shifted softmax;
// eps folded into clamp). wave = 2 dst nodes; per node 4 edge slots x 8 feat-lanes;
// lane holds 8 feats; next-edge ssrc/efb prefetched to pipeline the gather chain.
// residual from xb (bf16): xab = bf16(xb + agg).
__global__ __launch_bounds__(256) void k_agg(
    const ushort* __restrict__ xb, const ushort* __restrict__ efb,
    const int* __restrict__ ssrc, const int* __restrict__ rp,
    const float* __restrict__ We, const float* __restrict__ be,
    const float* __restrict__ betas, int layer, ushort* __restrict__ xab) {
    int lane = threadIdx.x & 63;
    int n = blockIdx.x * 8 + (threadIdx.x >> 6) * 2 + (lane >> 5);
    int slot = (lane >> 3) & 3;  // edge slot 0..3 within node
    int f8 = lane & 7;           // feature octet: feats 8*f8 .. 8*f8+7
    float beta = betas[layer];

    // per-lane We block we[k][j] = We[k*64 + f8*8 + j]  (64 VGPRs, fully unrolled)
    float we[8][8];
    #pragma unroll
    for (int k = 0; k < 8; ++k) {
        float4 a = *(const float4*)&We[k * 64 + f8 * 8];
        float4 b = *(const float4*)&We[k * 64 + f8 * 8 + 4];
        we[k][0] = a.x; we[k][1] = a.y; we[k][2] = a.z; we[k][3] = a.w;
        we[k][4] = b.x; we[k][5] = b.y; we[k][6] = b.z; we[k][7] = b.w;
    }
    float bev[8];
    {
        float4 a = *(const float4*)&be[f8 * 8];
        float4 b = *(const float4*)&be[f8 * 8 + 4];
        bev[0] = a.x; bev[1] = a.y; bev[2] = a.z; bev[3] = a.w;
        bev[4] = b.x; bev[5] = b.y; bev[6] = b.z; bev[7] = b.w;
    }

    int r0 = rp[n], r1 = rp[n + 1];
    float S[8], T[8];
    #pragma unroll
    for (int c = 0; c < 8; ++c) { S[c] = 0.f; T[c] = 0.f; }

    int i = r0 + slot;
    if (i < r1) {
        int scur = ssrc[i];
        uint4 ecur = *(const uint4*)&efb[(size_t)i * 8];
        for (; i < r1; i += 4) {
            int inext = i + 4;
            int snxt = 0;
            uint4 enxt = make_uint4(0, 0, 0, 0);
            if (inext < r1) {                        // prefetch next edge's ssrc/efb
                snxt = ssrc[inext];
                enxt = *(const uint4*)&efb[(size_t)inext * 8];
            }
            uint4 xv = *(const uint4*)&xb[(size_t)scur * 64 + 8 * f8];
            float ef8[8];
            ef8[0] = blo(ecur.x); ef8[1] = bhi(ecur.x);
            ef8[2] = blo(ecur.y); ef8[3] = bhi(ecur.y);
            ef8[4] = blo(ecur.z); ef8[5] = bhi(ecur.z);
            ef8[6] = blo(ecur.w); ef8[7] = bhi(ecur.w);
            float acc[8];
            #pragma unroll
            for (int j = 0; j < 8; ++j) acc[j] = bev[j];
            #pragma unroll
            for (int k = 0; k < 8; ++k)
                #pragma unroll
                for (int j = 0; j < 8; ++j) acc[j] = fmaf(ef8[k], we[k][j], acc[j]);
            float xf[8];
            xf[0] = blo(xv.x); xf[1] = bhi(xv.x);
            xf[2] = blo(xv.y); xf[3] = bhi(xv.y);
            xf[4] = blo(xv.z); xf[5] = bhi(xv.z);
            xf[6] = blo(xv.w); xf[7] = bhi(xv.w);
            #pragma unroll
            for (int c = 0; c < 8; ++c) {
                float m = fmaxf(xf[c] + acc[c], 1e-7f);
                float p = __expf(m * beta);
                S[c] += p;
                T[c] += m * p;
            }
            scur = snxt;
            ecur = enxt;
        }
    }
    // merge the 4 edge slots within each 32-lane node half (xor 8, 16)
    #pragma unroll
    for (int c = 0; c < 8; ++c) {
        #pragma unroll
        for (int d = 8; d <= 16; d <<= 1) {
            S[c] += __shfl_xor(S[c], d, 64);
            T[c] += __shfl_xor(T[c], d, 64);
        }
    }
    if (slot == 0) {
        bool has = r1 > r0;
        float a[8];
        #pragma unroll
        for (int c = 0; c < 8; ++c) a[c] = has ? (T[c] / S[c]) : 0.f;
        uint4 xv = *(const uint4*)&xb[(size_t)n * 64 + 8 * f8];
        uint4 pk;
        pk.x = f2b(blo(xv.x) + a[0]) | (f2b(bhi(xv.x) + a[1]) << 16);
        pk.y = f2b(blo(xv.y) + a[2]) | (f2b(bhi(xv.y) + a[3]) << 16);
        pk.z = f2b(blo(xv.z) + a[4]) | (f2b(bhi(xv.z) + a[5]) << 16);
        pk.w = f2b(blo(xv.w) + a[6]) | (f2b(bhi(xv.w) + a[7]) << 16);
        *(uint4*)&xab[(size_t)n * 64 + 8 * f8] = pk;
    }
}

// MFMA MLP: t1 = relu(LN(xab@W1 + b1)); h += t1@W2 + b2; xbout = bf16(relu(LN_next(h)))
__global__ __launch_bounds__(256) void k_mlp_mfma(
    const ushort* __restrict__ xab, const short* __restrict__ W1T, const float* __restrict__ b1,
    const float* __restrict__ g1, const float* __restrict__ bt1,
    const short* __restrict__ W2T, const float* __restrict__ b2,
    const float* __restrict__ ng, const float* __restrict__ nb,
    float* __restrict__ h, ushort* __restrict__ xbout) {
    __shared__ __align__(16) short W1s[8192];      // [o=128][k=64], XOR-swizzled
    __shared__ __align__(16) short W2s[8192];      // [o=64][k=128], XOR-swizzled
    __shared__ __align__(16) short xas[4][1024];   // per-wave [node=16][k=64]
    __shared__ __align__(16) short t1s[4][2048];   // per-wave [node=16][k=128]
    int tid = threadIdx.x;
    int lane = tid & 63, w = tid >> 6;

    {
        const int4* g1p = (const int4*)W1T;
        const int4* g2p = (const int4*)W2T;
        for (int u = tid; u < 1024; u += 256) {
            int byte = u * 16;
            int off1 = byte ^ ((((byte >> 7) & 7)) << 4);   // W1s rows = 128B
            *(int4*)((char*)W1s + off1) = g1p[u];
            int off2 = byte ^ ((((byte >> 8) & 7)) << 4);   // W2s rows = 256B
            *(int4*)((char*)W2s + off2) = g2p[u];
        }
    }
    int nbase = blockIdx.x * 64 + w * 16;
    #pragma unroll
    for (int it = 0; it < 2; ++it) {
        int idx = it * 512 + lane * 8;     // [16][64] bf16 elems
        int node = idx >> 6, k0 = idx & 63;
        int4 v = *(const int4*)&xab[(size_t)(nbase + node) * 64 + k0];
        int boff = (node * 128 + k0 * 2) ^ ((node & 7) << 4);
        *(int4*)((char*)xas[w] + boff) = v;
    }
    __syncthreads();

    int cg = lane >> 4;
    int cl = lane & 15;
    float b1v[8], g1v[8], t1bv[8];
    #pragma unroll
    for (int t = 0; t < 8; ++t) {
        b1v[t] = b1[t * 16 + cl]; g1v[t] = g1[t * 16 + cl]; t1bv[t] = bt1[t * 16 + cl];
    }
    f32x4 c1[8];
    #pragma unroll
    for (int t = 0; t < 8; ++t) c1[t] = (f32x4){b1v[t], b1v[t], b1v[t], b1v[t]};
    #pragma unroll
    for (int s = 0; s < 2; ++s) {
        int aoff = (cl * 128 + s * 64 + cg * 16) ^ ((cl & 7) << 4);
        short8v af = *(const short8v*)((char*)xas[w] + aoff);
        #pragma unroll
        for (int t = 0; t < 8; ++t) {
            int o = t * 16 + cl;
            int boff = (o * 128 + s * 64 + cg * 16) ^ ((o & 7) << 4);
            short8v bfv = *(const short8v*)((char*)W1s + boff);
            c1[t] = __builtin_amdgcn_mfma_f32_16x16x32_bf16(af, bfv, c1[t], 0, 0, 0);
        }
    }
    float sum[4] = {0, 0, 0, 0}, sq[4] = {0, 0, 0, 0};
    #pragma unroll
    for (int t = 0; t < 8; ++t)
        #pragma unroll
        for (int r = 0; r < 4; ++r) { sum[r] += c1[t][r]; sq[r] += c1[t][r] * c1[t][r]; }
    #pragma unroll
    for (int r = 0; r < 4; ++r)
        #pragma unroll
        for (int d = 1; d < 16; d <<= 1) {
            sum[r] += __shfl_xor(sum[r], d, 16);
            sq[r] += __shfl_xor(sq[r], d, 16);
        }
    float mu[4], rs[4];
    #pragma unroll
    for (int r = 0; r < 4; ++r) {
        mu[r] = sum[r] * (1.f / 128.f);
        float var = sq[r] * (1.f / 128.f) - mu[r] * mu[r];
        rs[r] = rsqrtf(var + 1e-5f);
    }
    #pragma unroll
    for (int t = 0; t < 8; ++t)
        #pragma unroll
        for (int r = 0; r < 4; ++r) {
            float v = fmaxf((c1[t][r] - mu[r]) * rs[r] * g1v[t] + t1bv[t], 0.f);
            int node = cg * 4 + r, o = t * 16 + cl;
            int boff = (node * 256 + o * 2) ^ ((node & 7) << 4);
            *(short*)((char*)t1s[w] + boff) = (short)f2b(v);
        }
    __syncthreads();
    float b2v[4], ngv[4], nbv[4];
    #pragma unroll
    for (int t = 0; t < 4; ++t) {
        b2v[t] = b2[t * 16 + cl]; ngv[t] = ng[t * 16 + cl]; nbv[t] = nb[t * 16 + cl];
    }
    f32x4 c2[4];
    #pragma unroll
    for (int t = 0; t < 4; ++t) c2[t] = (f32x4){b2v[t], b2v[t], b2v[t], b2v[t]};
    #pragma unroll
    for (int s = 0; s < 4; ++s) {
        int aoff = (cl * 256 + s * 64 + cg * 16) ^ ((cl & 7) << 4);
        short8v af = *(const short8v*)((char*)t1s[w] + aoff);
        #pragma unroll
        for (int t = 0; t < 4; ++t) {
            int o = t * 16 + cl;
            int boff = (o * 256 + s * 64 + cg * 16) ^ ((o & 7) << 4);
            short8v bfv = *(const short8v*)((char*)W2s + boff);
            c2[t] = __builtin_amdgcn_mfma_f32_16x16x32_bf16(af, bfv, c2[t], 0, 0, 0);
        }
    }
    float hv[4][4];
    #pragma unroll
    for (int t = 0; t < 4; ++t)
        #pragma unroll
        for (int r = 0; r < 4; ++r) {
            int node = nbase + cg * 4 + r, o = t * 16 + cl;
            float v = h[(size_t)node * 64 + o] + c2[t][r];
            h[(size_t)node * 64 + o] = v;
            hv[t][r] = v;
        }
    float s2[4] = {0, 0, 0, 0}, q2[4] = {0, 0, 0, 0};
    #pragma unroll
    for (int t = 0; t < 4; ++t)
        #pragma unroll
        for (int r = 0; r < 4; ++r) { s2[r] += hv[t][r]; q2[r] += hv[t][r] * hv[t][r]; }
    #pragma unroll
    for (int r = 0; r < 4; ++r)
        #pragma unroll
        for (int d = 1; d < 16; d <<= 1) {
            s2[r] += __shfl_xor(s2[r], d, 16);
            q2[r] += __shfl_xor(q2[r], d, 16);
        }
    #pragma unroll
    for (int r = 0; r < 4; ++r) {
        float m2 = s2[r] * (1.f / 64.f);
        float var = q2[r] * (1.f / 64.f) - m2 * m2;
        float rv = rsqrtf(var + 1e-5f);
        #pragma unroll
        for (int t = 0; t < 4; ++t) {
            int node = nbase + cg * 4 + r, o = t * 16 + cl;
            float xv = fmaxf((hv[t][r] - m2) * rv * ngv[t] + nbv[t], 0.f);
            xbout[(size_t)node * 64 + o] = (ushort)f2b(xv);
        }
    }
}

// MFMA output linear: out = xb@W_out + b_out. wave = 16 nodes, 7 o-tiles of 16.
__global__ __launch_bounds__(256) void k_out_mfma(
    const ushort* __restrict__ xb, const short* __restrict__ WoT, const float* __restrict__ bo,
    float* __restrict__ out) {
    __shared__ __align__(16) short Wos[OUT_DIM * 64];  // [o=112][k=64], XOR-swizzled
    __shared__ __align__(16) short xs[4][1024];        // per-wave [node=16][k=64]
    int tid = threadIdx.x, lane = tid & 63, w = tid >> 6;

    {
        const int4* gp = (const int4*)WoT;
        for (int u = tid; u < OUT_DIM * 8; u += 256) {  // 896 int4 units
            int byte = u * 16;
            int off = byte ^ (((byte >> 7) & 7) << 4);  // rows = 128B
            *(int4*)((char*)Wos + off) = gp[u];
        }
    }
    int nbase = blockIdx.x * 64 + w * 16;
    #pragma unroll
    for (int it = 0; it < 2; ++it) {
        int idx = it * 512 + lane * 8;     // [16][64] bf16 elems
        int node = idx >> 6, k0 = idx & 63;
        int4 v = *(const int4*)&xb[(size_t)(nbase + node) * 64 + k0];
        int boff = (node * 128 + k0 * 2) ^ ((node & 7) << 4);
        *(int4*)((char*)xs[w] + boff) = v;
    }
    __syncthreads();

    int cg = lane >> 4, cl = lane & 15;
    f32x4 c[7];
    #pragma unroll
    for (int t = 0; t < 7; ++t) {
        float bv = bo[t * 16 + cl];
        c[t] = (f32x4){bv, bv, bv, bv};
    }
    #pragma unroll
    for (int s = 0; s < 2; ++s) {
        int aoff = (cl * 128 + s * 64 + cg * 16) ^ ((cl & 7) << 4);
        short8v af = *(const short8v*)((char*)xs[w] + aoff);
        #pragma unroll
        for (int t = 0; t < 7; ++t) {
            int o = t * 16 + cl;
            int boff = (o * 128 + s * 64 + cg * 16) ^ ((o & 7) << 4);
            short8v bfv = *(const short8v*)((char*)Wos + boff);
            c[t] = __builtin_amdgcn_mfma_f32_16x16x32_bf16(af, bfv, c[t], 0, 0, 0);
        }
    }
    #pragma unroll
    for (int t = 0; t < 7; ++t)
        #pragma unroll
        for (int r = 0; r < 4; ++r) {
            int node = nbase + cg * 4 + r;
            if (node < N_NODES) out[(size_t)node * OUT_DIM + t * 16 + cl] = c[t][r];
        }
}

// ---------------- launcher ----------------

extern "C" void kernel_launch(void* const* d_in, const int* in_sizes, int n_in,
                              void* d_out, int out_size, void* d_ws, size_t ws_size,
                              hipStream_t stream) {
    (void)in_sizes; (void)n_in; (void)out_size; (void)ws_size;
    const float* node_feats = (const float*)d_in[0];
    const float* edge_feats = (const float*)d_in[1];
    const int*   src        = (const int*)d_in[2];
    const int*   dst        = (const int*)d_in[3];
    const float* W_node     = (const float*)d_in[4];
    const float* b_node     = (const float*)d_in[5];
    const float* W_edge     = (const float*)d_in[6];
    const float* b_edge     = (const float*)d_in[7];
    const float* betas      = (const float*)d_in[8];
    const float* W1         = (const float*)d_in[9];
    const float* b1         = (const float*)d_in[10];
    const float* ln1_g      = (const float*)d_in[11];
    const float* ln1_b      = (const float*)d_in[12];
    const float* W2         = (const float*)d_in[13];
    const float* b2         = (const float*)d_in[14];
    const float* norm_g     = (const float*)d_in[15];
    const float* norm_b     = (const float*)d_in[16];
    const float* W_out      = (const float*)d_in[17];
    const float* b_out      = (const float*)d_in[18];
    float* out = (float*)d_out;

    char* p = (char*)d_ws;
    auto carve = [&](size_t bytes) {
        char* r = p;
        p += (bytes + 255) & ~(size_t)255;
        return r;
    };
    float*  h    = (float*)carve((size_t)N_PAD * 64 * sizeof(float));
    ushort* xb   = (ushort*)carve((size_t)N_PAD * 64 * sizeof(short));
    ushort* xab  = (ushort*)carve((size_t)N_PAD * 64 * sizeof(short));
    ushort* efb  = (ushort*)carve((size_t)N_EDGES * 8 * sizeof(short));
    int* rp   = (int*)carve((size_t)(N_NODES + 1) * sizeof(int));
    int* nxt  = (int*)carve((size_t)N_NODES * sizeof(int));
    int* inc  = (int*)carve((size_t)N_NODES * sizeof(int));
    int* ssrc = (int*)carve((size_t)N_EDGES * sizeof(int));
    int* rank = (int*)carve((size_t)N_EDGES * sizeof(int));
    int* bsum = (int*)carve(512 * sizeof(int));
    int* boff = (int*)carve(512 * sizeof(int));
    short* W1T = (short*)carve((size_t)NLAYERS * 8192 * sizeof(short));
    short* W2T = (short*)carve((size_t)NLAYERS * 8192 * sizeof(short));
    short* WnT = (short*)carve((size_t)8192 * sizeof(short));
    short* WoT = (short*)carve((size_t)OUT_DIM * 64 * sizeof(short));

    // CSR by dst: one atomic pass (rank) + scan; positions computed in k_perm
    hipMemsetAsync(nxt, 0, (size_t)N_NODES * sizeof(int), stream);
    k_rank<<<(N_EDGES / 4 + 255) / 256, 256, 0, stream>>>(dst, nxt, rank);
    k_scan_a<<<SCAN_BLOCKS, 256, 0, stream>>>(nxt, inc, bsum);
    k_scan_b<<<1, 512, 0, stream>>>(bsum, boff, SCAN_BLOCKS);
    k_scan_c<<<SCAN_BLOCKS, 256, 0, stream>>>(inc, boff, rp);

    // weight prep + encoders (node_enc fuses layer-0 LN/ReLU); edge permute
    k_prep_w<<<(NLAYERS * 8192 + 255) / 256, 256, 0, stream>>>(W1, W2, W_node, W_out,
                                                               W1T, W2T, WnT, WoT);
    k_node_enc_mfma<<<N_PAD / 64, 256, 0, stream>>>(node_feats, WnT, b_node, norm_g, norm_b, h, xb);
    k_perm<<<(N_EDGES / 2 + 255) / 256, 256, 0, stream>>>(edge_feats, dst, rank, rp, src,
                                                          ssrc, efb);

    // layers; k_mlp_mfma epilogue produces xb for layer i+1 (final uses norm[0])
    for (int i = 0; i < NLAYERS; ++i) {
        int ni = (i + 1 < NLAYERS) ? (i + 1) : 0;
        k_agg<<<N_NODES / 8, 256, 0, stream>>>(xb, efb, ssrc, rp, W_edge, b_edge,
                                               betas, i, xab);
        k_mlp_mfma<<<N_PAD / 64, 256, 0, stream>>>(xab, W1T + i * 8192, b1 + i * 128,
                                                   ln1_g + i * 128, ln1_b + i * 128,
                                                   W2T + i * 8192, b2 + i * 64,
                                                   norm_g + ni * 64, norm_b + ni * 64,
                                                   h, xb);
    }

    // output linear (xb already = bf16(relu(LN_0(h))) from last mlp epilogue)
    k_out_mfma<<<N_PAD / 64, 256, 0, stream>>>(xb, WoT, b_out, out);
}

// Round 12
// 680.737 us; speedup vs baseline: 1.2350x; 1.2350x over previous
//
#include <hip/hip_runtime.h>
#include <hip/hip_bf16.h>

#define N_NODES 100000
#define N_PAD   100032   // 1563 * 64, padding for guard-free MFMA
#define N_EDGES 1200000
#define HID 64
#define OUT_DIM 112
#define NLAYERS 7

static constexpr int SCAN_BLOCKS = (N_NODES + 255) / 256;  // 391

typedef __attribute__((ext_vector_type(8))) short short8v;
typedef __attribute__((ext_vector_type(4))) float f32x4;
typedef unsigned int uint;
typedef unsigned short ushort;

__device__ __forceinline__ unsigned f2b(float f) {
    unsigned u = __builtin_bit_cast(unsigned, f);
    return (u + 0x7FFFu + ((u >> 16) & 1u)) >> 16;   // RNE bf16 bits in low 16
}
__device__ __forceinline__ float blo(uint v) {
    return __builtin_bit_cast(float, (v & 0xFFFFu) << 16);
}
__device__ __forceinline__ float bhi(uint v) {
    return __builtin_bit_cast(float, v & 0xFFFF0000u);
}

// ---------------- CSR build (rank-based) ----------------

__global__ __launch_bounds__(256) void k_rank(const int* __restrict__ dst, int* __restrict__ cnt,
                                              int* __restrict__ rank) {
    int e0 = (blockIdx.x * 256 + threadIdx.x) * 4;
    if (e0 + 3 < N_EDGES) {
        int4 d4 = *(const int4*)&dst[e0];
        int r0 = atomicAdd(&cnt[d4.x], 1);
        int r1 = atomicAdd(&cnt[d4.y], 1);
        int r2 = atomicAdd(&cnt[d4.z], 1);
        int r3 = atomicAdd(&cnt[d4.w], 1);
        *(int4*)&rank[e0] = make_int4(r0, r1, r2, r3);
    } else {
        for (int e = e0; e < N_EDGES; ++e) rank[e] = atomicAdd(&cnt[dst[e]], 1);
    }
}

__global__ __launch_bounds__(256) void k_scan_a(const int* __restrict__ cnt, int* __restrict__ inc,
                                                int* __restrict__ bsum) {
    __shared__ int lds[4];
    int i = blockIdx.x * 256 + threadIdx.x;
    int v = (i < N_NODES) ? cnt[i] : 0;
    int lane = threadIdx.x & 63, w = threadIdx.x >> 6;
    #pragma unroll
    for (int d = 1; d < 64; d <<= 1) {
        int u = __shfl_up(v, d, 64);
        if (lane >= d) v += u;
    }
    if (lane == 63) lds[w] = v;
    __syncthreads();
    int add = 0;
    for (int j = 0; j < w; ++j) add += lds[j];
    v += add;
    if (i < N_NODES) inc[i] = v;
    if (threadIdx.x == 255) bsum[blockIdx.x] = v;
}

__global__ __launch_bounds__(512) void k_scan_b(const int* __restrict__ bsum, int* __restrict__ boff, int nb) {
    __shared__ int lds[8];
    int t = threadIdx.x;
    int v0 = (t < nb) ? bsum[t] : 0;
    int v = v0;
    int lane = t & 63, w = t >> 6;
    #pragma unroll
    for (int d = 1; d < 64; d <<= 1) {
        int u = __shfl_up(v, d, 64);
        if (lane >= d) v += u;
    }
    if (lane == 63) lds[w] = v;
    __syncthreads();
    int add = 0;
    for (int j = 0; j < w; ++j) add += lds[j];
    boff[t] = v + add - v0;  // exclusive prefix
}

__global__ __launch_bounds__(256) void k_scan_c(const int* __restrict__ inc, const int* __restrict__ boff,
                                                int* __restrict__ rp) {
    int i = blockIdx.x * 256 + threadIdx.x;
    if (i < N_NODES) {
        rp[i + 1] = inc[i] + boff[blockIdx.x];
        if (i == 0) rp[0] = 0;
    }
}

// ---------------- weight prep: transpose + bf16 ----------------
__global__ __launch_bounds__(256) void k_prep_w(const float* __restrict__ W1, const float* __restrict__ W2,
                                                const float* __restrict__ Wn, const float* __restrict__ Wo,
                                                short* __restrict__ W1T, short* __restrict__ W2T,
                                                short* __restrict__ WnT, short* __restrict__ WoT) {
    int t = blockIdx.x * 256 + threadIdx.x;
    if (t < NLAYERS * 8192) {
        int l = t >> 13, r = t & 8191;
        int o1 = r >> 6, k1 = r & 63;
        W1T[t] = (short)f2b(W1[l * 8192 + k1 * 128 + o1]);
        int o2 = r >> 7, k2 = r & 127;
        W2T[t] = (short)f2b(W2[l * 8192 + k2 * 64 + o2]);
        if (t < 8192) {
            int o = t >> 7, k = t & 127;
            WnT[t] = (short)f2b(Wn[k * 64 + o]);
        }
        if (t < OUT_DIM * 64) {
            int o = t >> 6, k = t & 63;
            WoT[t] = (short)f2b(Wo[k * OUT_DIM + o]);
        }
    }
}

// ---------------- encoders ----------------

// MFMA node encoder: h = nf@Wn + bn; xb = bf16(relu(LN0(h))).
// A-frags loaded DIRECTLY from global nf (8 contiguous f32/lane), no LDS staging.
__global__ __launch_bounds__(256) void k_node_enc_mfma(
    const float* __restrict__ nf, const short* __restrict__ WnT, const float* __restrict__ bn,
    const float* __restrict__ g, const float* __restrict__ b,
    float* __restrict__ h, ushort* __restrict__ xb) {
    __shared__ __align__(16) short Wns[8192];      // [o=64][k=128], XOR-swizzled
    int tid = threadIdx.x, lane = tid & 63, w = tid >> 6;

    {
        const int4* gp = (const int4*)WnT;
        for (int u = tid; u < 1024; u += 256) {
            int byte = u * 16;
            int off = byte ^ (((byte >> 8) & 7) << 4);   // rows = 256B
            *(int4*)((char*)Wns + off) = gp[u];
        }
    }
    __syncthreads();

    int nbase = blockIdx.x * 64 + w * 16;
    int cg = lane >> 4, cl = lane & 15;
    int arow = nbase + cl;
    bool in = arow < N_NODES;

    float bv[4], gv[4], bbv[4];
    #pragma unroll
    for (int t = 0; t < 4; ++t) {
        bv[t] = bn[t * 16 + cl]; gv[t] = g[t * 16 + cl]; bbv[t] = b[t * 16 + cl];
    }
    f32x4 c[4];
    #pragma unroll
    for (int t = 0; t < 4; ++t) c[t] = (f32x4){bv[t], bv[t], bv[t], bv[t]};
    #pragma unroll
    for (int s = 0; s < 4; ++s) {
        int k0 = s * 32 + cg * 8;
        float4 a0 = in ? *(const float4*)&nf[(size_t)arow * 128 + k0]
                       : make_float4(0.f, 0.f, 0.f, 0.f);
        float4 a1 = in ? *(const float4*)&nf[(size_t)arow * 128 + k0 + 4]
                       : make_float4(0.f, 0.f, 0.f, 0.f);
        short8v af;
        af[0] = (short)f2b(a0.x); af[1] = (short)f2b(a0.y);
        af[2] = (short)f2b(a0.z); af[3] = (short)f2b(a0.w);
        af[4] = (short)f2b(a1.x); af[5] = (short)f2b(a1.y);
        af[6] = (short)f2b(a1.z); af[7] = (short)f2b(a1.w);
        #pragma unroll
        for (int t = 0; t < 4; ++t) {
            int o = t * 16 + cl;
            int boff = (o * 256 + s * 64 + cg * 16) ^ ((o & 7) << 4);
            short8v bfv = *(const short8v*)((char*)Wns + boff);
            c[t] = __builtin_amdgcn_mfma_f32_16x16x32_bf16(af, bfv, c[t], 0, 0, 0);
        }
    }
    float s2[4] = {0, 0, 0, 0}, q2[4] = {0, 0, 0, 0};
    #pragma unroll
    for (int t = 0; t < 4; ++t)
        #pragma unroll
        for (int r = 0; r < 4; ++r) {
            int node = nbase + cg * 4 + r, o = t * 16 + cl;
            h[(size_t)node * 64 + o] = c[t][r];
            s2[r] += c[t][r]; q2[r] += c[t][r] * c[t][r];
        }
    #pragma unroll
    for (int r = 0; r < 4; ++r)
        #pragma unroll
        for (int d = 1; d < 16; d <<= 1) {
            s2[r] += __shfl_xor(s2[r], d, 16);
            q2[r] += __shfl_xor(q2[r], d, 16);
        }
    #pragma unroll
    for (int r = 0; r < 4; ++r) {
        float mu = s2[r] * (1.f / 64.f);
        float var = q2[r] * (1.f / 64.f) - mu * mu;
        float rv = rsqrtf(var + 1e-5f);
        #pragma unroll
        for (int t = 0; t < 4; ++t) {
            int node = nbase + cg * 4 + r, o = t * 16 + cl;
            float xv = fmaxf((c[t][r] - mu) * rv * gv[t] + bbv[t], 0.f);
            xb[(size_t)node * 64 + o] = (ushort)f2b(xv);
        }
    }
}

// edge encoder (R8 structure): LDS-stage 256 edges/block, wave computes 64 edges;
// p = rp[dst[e]] + rank[e]; ssrc[p] = src[e]; scatter-write bf16 eh rows (full 128B rows).
__global__ __launch_bounds__(256) void k_edge_enc(
    const float* __restrict__ ef, const float* __restrict__ We, const float* __restrict__ be,
    const int* __restrict__ dst, const int* __restrict__ rank, const int* __restrict__ rp,
    const int* __restrict__ src, int* __restrict__ ssrc, ushort* __restrict__ eh) {
    __shared__ float efs[2048];   // 256 edges x 8 feats
    int tid = threadIdx.x, lane = tid & 63, w = tid >> 6;
    float wreg[8];
    #pragma unroll
    for (int k = 0; k < 8; ++k) wreg[k] = We[k * 64 + lane];
    float bv = be[lane];
    int base = blockIdx.x * 256;
    if (base >= N_EDGES) return;
    #pragma unroll
    for (int u = 0; u < 2; ++u) {
        int idx = u * 1024 + tid * 4;
        size_t gidx = (size_t)base * 8 + idx;
        float4 v = (gidx < (size_t)N_EDGES * 8) ? *(const float4*)&ef[gidx]
                                                : make_float4(0.f, 0.f, 0.f, 0.f);
        *(float4*)&efs[idx] = v;
    }
    int ge0 = base + w * 64 + lane;
    int myp = -1;
    if (ge0 < N_EDGES) {
        myp = rp[dst[ge0]] + rank[ge0];
        ssrc[myp] = src[ge0];
    }
    __syncthreads();
    #pragma unroll 4
    for (int j = 0; j < 64; ++j) {
        int p = __shfl(myp, j, 64);
        if (p >= 0) {
            float4 a = *(const float4*)&efs[(w * 64 + j) * 8];
            float4 b = *(const float4*)&efs[(w * 64 + j) * 8 + 4];
            float acc = bv;
            acc = fmaf(a.x, wreg[0], acc); acc = fmaf(a.y, wreg[1], acc);
            acc = fmaf(a.z, wreg[2], acc); acc = fmaf(a.w, wreg[3], acc);
            acc = fmaf(b.x, wreg[4], acc); acc = fmaf(b.y, wreg[5], acc);
            acc = fmaf(b.z, wreg[6], acc); acc = fmaf(b.w, wreg[7], acc);
            eh[(size_t)p * 64 + lane] = (ushort)f2b(acc);
        }
    }
}

// ---------------- per-layer kernels ----------------

// aggregation (R8 structure, eps folded into clamp). No max-subtraction
// (logits bounded ~9 -> exp safe in f32; T/S == shifted softmax).
// wave = 2 dst nodes; per node 4 edge slots x 8 feat-lanes; lane holds 8 feats;
// slot loop paired (i, i+4 in flight). residual from xb: xab = bf16(xb + agg).
__global__ __launch_bounds__(256) void k_agg(
    const ushort* __restrict__ xb, const ushort* __restrict__ eh,
    const int* __restrict__ ssrc, const int* __restrict__ rp,
    const float* __restrict__ betas, int layer, ushort* __restrict__ xab) {
    int lane = threadIdx.x & 63;
    int n = blockIdx.x * 8 + (threadIdx.x >> 6) * 2 + (lane >> 5);
    int slot = (lane >> 3) & 3;  // edge slot 0..3 within node
    int f8 = lane & 7;           // feature octet: feats 8*f8 .. 8*f8+7
    float beta = betas[layer];
    int r0 = rp[n], r1 = rp[n + 1];
    float S[8], T[8];
    #pragma unroll
    for (int c = 0; c < 8; ++c) { S[c] = 0.f; T[c] = 0.f; }
    int i = r0 + slot;
    for (; i + 4 < r1; i += 8) {   // this slot: edges i and i+4, both in flight
        int sA = ssrc[i], sB = ssrc[i + 4];
        uint4 xvA = *(const uint4*)&xb[(size_t)sA * 64 + 8 * f8];
        uint4 evA = *(const uint4*)&eh[(size_t)i * 64 + 8 * f8];
        uint4 xvB = *(const uint4*)&xb[(size_t)sB * 64 + 8 * f8];
        uint4 evB = *(const uint4*)&eh[(size_t)(i + 4) * 64 + 8 * f8];
        float mA[8], mB[8];
        mA[0] = fmaxf(blo(xvA.x) + blo(evA.x), 1e-7f);
        mA[1] = fmaxf(bhi(xvA.x) + bhi(evA.x), 1e-7f);
        mA[2] = fmaxf(blo(xvA.y) + blo(evA.y), 1e-7f);
        mA[3] = fmaxf(bhi(xvA.y) + bhi(evA.y), 1e-7f);
        mA[4] = fmaxf(blo(xvA.z) + blo(evA.z), 1e-7f);
        mA[5] = fmaxf(bhi(xvA.z) + bhi(evA.z), 1e-7f);
        mA[6] = fmaxf(blo(xvA.w) + blo(evA.w), 1e-7f);
        mA[7] = fmaxf(bhi(xvA.w) + bhi(evA.w), 1e-7f);
        mB[0] = fmaxf(blo(xvB.x) + blo(evB.x), 1e-7f);
        mB[1] = fmaxf(bhi(xvB.x) + bhi(evB.x), 1e-7f);
        mB[2] = fmaxf(blo(xvB.y) + blo(evB.y), 1e-7f);
        mB[3] = fmaxf(bhi(xvB.y) + bhi(evB.y), 1e-7f);
        mB[4] = fmaxf(blo(xvB.z) + blo(evB.z), 1e-7f);
        mB[5] = fmaxf(bhi(xvB.z) + bhi(evB.z), 1e-7f);
        mB[6] = fmaxf(blo(xvB.w) + blo(evB.w), 1e-7f);
        mB[7] = fmaxf(bhi(xvB.w) + bhi(evB.w), 1e-7f);
        #pragma unroll
        for (int c = 0; c < 8; ++c) {
            float pA = __expf(mA[c] * beta);
            float pB = __expf(mB[c] * beta);
            S[c] += pA + pB;
            T[c] += mA[c] * pA + mB[c] * pB;
        }
    }
    for (; i < r1; i += 4) {
        int s0 = ssrc[i];
        uint4 xv = *(const uint4*)&xb[(size_t)s0 * 64 + 8 * f8];
        uint4 ev = *(const uint4*)&eh[(size_t)i * 64 + 8 * f8];
        float m[8];
        m[0] = fmaxf(blo(xv.x) + blo(ev.x), 1e-7f);
        m[1] = fmaxf(bhi(xv.x) + bhi(ev.x), 1e-7f);
        m[2] = fmaxf(blo(xv.y) + blo(ev.y), 1e-7f);
        m[3] = fmaxf(bhi(xv.y) + bhi(ev.y), 1e-7f);
        m[4] = fmaxf(blo(xv.z) + blo(ev.z), 1e-7f);
        m[5] = fmaxf(bhi(xv.z) + bhi(ev.z), 1e-7f);
        m[6] = fmaxf(blo(xv.w) + blo(ev.w), 1e-7f);
        m[7] = fmaxf(bhi(xv.w) + bhi(ev.w), 1e-7f);
        #pragma unroll
        for (int c = 0; c < 8; ++c) {
            float p = __expf(m[c] * beta);
            S[c] += p;
            T[c] += m[c] * p;
        }
    }
    // merge the 4 edge slots within each 32-lane node half (xor 8, 16)
    #pragma unroll
    for (int c = 0; c < 8; ++c) {
        #pragma unroll
        for (int d = 8; d <= 16; d <<= 1) {
            S[c] += __shfl_xor(S[c], d, 64);
            T[c] += __shfl_xor(T[c], d, 64);
        }
    }
    if (slot == 0) {
        bool has = r1 > r0;
        float a[8];
        #pragma unroll
        for (int c = 0; c < 8; ++c) a[c] = has ? (T[c] / S[c]) : 0.f;
        uint4 xv = *(const uint4*)&xb[(size_t)n * 64 + 8 * f8];
        uint4 pk;
        pk.x = f2b(blo(xv.x) + a[0]) | (f2b(bhi(xv.x) + a[1]) << 16);
        pk.y = f2b(blo(xv.y) + a[2]) | (f2b(bhi(xv.y) + a[3]) << 16);
        pk.z = f2b(blo(xv.z) + a[4]) | (f2b(bhi(xv.z) + a[5]) << 16);
        pk.w = f2b(blo(xv.w) + a[6]) | (f2b(bhi(xv.w) + a[7]) << 16);
        *(uint4*)&xab[(size_t)n * 64 + 8 * f8] = pk;
    }
}

// MFMA MLP: t1 = relu(LN(xab@W1 + b1)); h += t1@W2 + b2; xbout = bf16(relu(LN_next(h))).
// GEMM1 A-frags loaded DIRECTLY from global xab (16B/lane); only one barrier
// (after W staging); t1s is wave-local. LDS 48KB -> 3 blocks/CU.
__global__ __launch_bounds__(256) void k_mlp_mfma(
    const ushort* __restrict__ xab, const short* __restrict__ W1T, const float* __restrict__ b1,
    const float* __restrict__ g1, const float* __restrict__ bt1,
    const short* __restrict__ W2T, const float* __restrict__ b2,
    const float* __restrict__ ng, const float* __restrict__ nb,
    float* __restrict__ h, ushort* __restrict__ xbout) {
    __shared__ __align__(16) short W1s[8192];      // [o=128][k=64], XOR-swizzled
    __shared__ __align__(16) short W2s[8192];      // [o=64][k=128], XOR-swizzled
    __shared__ __align__(16) short t1s[4][2048];   // per-wave [node=16][k=128]
    int tid = threadIdx.x;
    int lane = tid & 63, w = tid >> 6;

    {
        const int4* g1p = (const int4*)W1T;
        const int4* g2p = (const int4*)W2T;
        for (int u = tid; u < 1024; u += 256) {
            int byte = u * 16;
            int off1 = byte ^ ((((byte >> 7) & 7)) << 4);   // W1s rows = 128B
            *(int4*)((char*)W1s + off1) = g1p[u];
            int off2 = byte ^ ((((byte >> 8) & 7)) << 4);   // W2s rows = 256B
            *(int4*)((char*)W2s + off2) = g2p[u];
        }
    }
    __syncthreads();

    int nbase = blockIdx.x * 64 + w * 16;
    int cg = lane >> 4;
    int cl = lane & 15;
    float b1v[8], g1v[8], t1bv[8];
    #pragma unroll
    for (int t = 0; t < 8; ++t) {
        b1v[t] = b1[t * 16 + cl]; g1v[t] = g1[t * 16 + cl]; t1bv[t] = bt1[t * 16 + cl];
    }
    f32x4 c1[8];
    #pragma unroll
    for (int t = 0; t < 8; ++t) c1[t] = (f32x4){b1v[t], b1v[t], b1v[t], b1v[t]};
    #pragma unroll
    for (int s = 0; s < 2; ++s) {
        short8v af = *(const short8v*)&xab[(size_t)(nbase + cl) * 64 + s * 32 + cg * 8];
        #pragma unroll
        for (int t = 0; t < 8; ++t) {
            int o = t * 16 + cl;
            int boff = (o * 128 + s * 64 + cg * 16) ^ ((o & 7) << 4);
            short8v bfv = *(const short8v*)((char*)W1s + boff);
            c1[t] = __builtin_amdgcn_mfma_f32_16x16x32_bf16(af, bfv, c1[t], 0, 0, 0);
        }
    }
    float sum[4] = {0, 0, 0, 0}, sq[4] = {0, 0, 0, 0};
    #pragma unroll
    for (int t = 0; t < 8; ++t)
        #pragma unroll
        for (int r = 0; r < 4; ++r) { sum[r] += c1[t][r]; sq[r] += c1[t][r] * c1[t][r]; }
    #pragma unroll
    for (int r = 0; r < 4; ++r)
        #pragma unroll
        for (int d = 1; d < 16; d <<= 1) {
            sum[r] += __shfl_xor(sum[r], d, 16);
            sq[r] += __shfl_xor(sq[r], d, 16);
        }
    float mu[4], rs[4];
    #pragma unroll
    for (int r = 0; r < 4; ++r) {
        mu[r] = sum[r] * (1.f / 128.f);
        float var = sq[r] * (1.f / 128.f) - mu[r] * mu[r];
        rs[r] = rsqrtf(var + 1e-5f);
    }
    #pragma unroll
    for (int t = 0; t < 8; ++t)
        #pragma unroll
        for (int r = 0; r < 4; ++r) {
            float v = fmaxf((c1[t][r] - mu[r]) * rs[r] * g1v[t] + t1bv[t], 0.f);
            int node = cg * 4 + r, o = t * 16 + cl;
            int boff = (node * 256 + o * 2) ^ ((node & 7) << 4);
            *(short*)((char*)t1s[w] + boff) = (short)f2b(v);
        }
    // t1s is wave-local: writes then reads by the same wave -> no barrier needed
    float b2v[4], ngv[4], nbv[4];
    #pragma unroll
    for (int t = 0; t < 4; ++t) {
        b2v[t] = b2[t * 16 + cl]; ngv[t] = ng[t * 16 + cl]; nbv[t] = nb[t * 16 + cl];
    }
    f32x4 c2[4];
    #pragma unroll
    for (int t = 0; t < 4; ++t) c2[t] = (f32x4){b2v[t], b2v[t], b2v[t], b2v[t]};
    #pragma unroll
    for (int s = 0; s < 4; ++s) {
        int aoff = (cl * 256 + s * 64 + cg * 16) ^ ((cl & 7) << 4);
        short8v af = *(const short8v*)((char*)t1s[w] + aoff);
        #pragma unroll
        for (int t = 0; t < 4; ++t) {
            int o = t * 16 + cl;
            int boff = (o * 256 + s * 64 + cg * 16) ^ ((o & 7) << 4);
            short8v bfv = *(const short8v*)((char*)W2s + boff);
            c2[t] = __builtin_amdgcn_mfma_f32_16x16x32_bf16(af, bfv, c2[t], 0, 0, 0);
        }
    }
    float hv[4][4];
    #pragma unroll
    for (int t = 0; t < 4; ++t)
        #pragma unroll
        for (int r = 0; r < 4; ++r) {
            int node = nbase + cg * 4 + r, o = t * 16 + cl;
            float v = h[(size_t)node * 64 + o] + c2[t][r];
            h[(size_t)node * 64 + o] = v;
            hv[t][r] = v;
        }
    float s2[4] = {0, 0, 0, 0}, q2[4] = {0, 0, 0, 0};
    #pragma unroll
    for (int t = 0; t < 4; ++t)
        #pragma unroll
        for (int r = 0; r < 4; ++r) { s2[r] += hv[t][r]; q2[r] += hv[t][r] * hv[t][r]; }
    #pragma unroll
    for (int r = 0; r < 4; ++r)
        #pragma unroll
        for (int d = 1; d < 16; d <<= 1) {
            s2[r] += __shfl_xor(s2[r], d, 16);
            q2[r] += __shfl_xor(q2[r], d, 16);
        }
    #pragma unroll
    for (int r = 0; r < 4; ++r) {
        float m2 = s2[r] * (1.f / 64.f);
        float var = q2[r] * (1.f / 64.f) - m2 * m2;
        float rv = rsqrtf(var + 1e-5f);
        #pragma unroll
        for (int t = 0; t < 4; ++t) {
            int node = nbase + cg * 4 + r, o = t * 16 + cl;
            float xv = fmaxf((hv[t][r] - m2) * rv * ngv[t] + nbv[t], 0.f);
            xbout[(size_t)node * 64 + o] = (ushort)f2b(xv);
        }
    }
}

// MFMA output linear: out = xb@W_out + b_out. A-frags direct from global xb.
__global__ __launch_bounds__(256) void k_out_mfma(
    const ushort* __restrict__ xb, const short* __restrict__ WoT, const float* __restrict__ bo,
    float* __restrict__ out) {
    __shared__ __align__(16) short Wos[OUT_DIM * 64];  // [o=112][k=64], XOR-swizzled
    int tid = threadIdx.x, lane = tid & 63, w = tid >> 6;

    {
        const int4* gp = (const int4*)WoT;
        for (int u = tid; u < OUT_DIM * 8; u += 256) {  // 896 int4 units
            int byte = u * 16;
            int off = byte ^ (((byte >> 7) & 7) << 4);  // rows = 128B
            *(int4*)((char*)Wos + off) = gp[u];
        }
    }
    __syncthreads();

    int nbase = blockIdx.x * 64 + w * 16;
    int cg = lane >> 4, cl = lane & 15;
    f32x4 c[7];
    #pragma unroll
    for (int t = 0; t < 7; ++t) {
        float bv = bo[t * 16 + cl];
        c[t] = (f32x4){bv, bv, bv, bv};
    }
    #pragma unroll
    for (int s = 0; s < 2; ++s) {
        short8v af = *(const short8v*)&xb[(size_t)(nbase + cl) * 64 + s * 32 + cg * 8];
        #pragma unroll
        for (int t = 0; t < 7; ++t) {
            int o = t * 16 + cl;
            int boff = (o * 128 + s * 64 + cg * 16) ^ ((o & 7) << 4);
            short8v bfv = *(const short8v*)((char*)Wos + boff);
            c[t] = __builtin_amdgcn_mfma_f32_16x16x32_bf16(af, bfv, c[t], 0, 0, 0);
        }
    }
    #pragma unroll
    for (int t = 0; t < 7; ++t)
        #pragma unroll
        for (int r = 0; r < 4; ++r) {
            int node = nbase + cg * 4 + r;
            if (node < N_NODES) out[(size_t)node * OUT_DIM + t * 16 + cl] = c[t][r];
        }
}

// ---------------- launcher ----------------

extern "C" void kernel_launch(void* const* d_in, const int* in_sizes, int n_in,
                              void* d_out, int out_size, void* d_ws, size_t ws_size,
                              hipStream_t stream) {
    (void)in_sizes; (void)n_in; (void)out_size; (void)ws_size;
    const float* node_feats = (const float*)d_in[0];
    const float* edge_feats = (const float*)d_in[1];
    const int*   src        = (const int*)d_in[2];
    const int*   dst        = (const int*)d_in[3];
    const float* W_node     = (const float*)d_in[4];
    const float* b_node     = (const float*)d_in[5];
    const float* W_edge     = (const float*)d_in[6];
    const float* b_edge     = (const float*)d_in[7];
    const float* betas      = (const float*)d_in[8];
    const float* W1         = (const float*)d_in[9];
    const float* b1         = (const float*)d_in[10];
    const float* ln1_g      = (const float*)d_in[11];
    const float* ln1_b      = (const float*)d_in[12];
    const float* W2         = (const float*)d_in[13];
    const float* b2         = (const float*)d_in[14];
    const float* norm_g     = (const float*)d_in[15];
    const float* norm_b     = (const float*)d_in[16];
    const float* W_out      = (const float*)d_in[17];
    const float* b_out      = (const float*)d_in[18];
    float* out = (float*)d_out;

    char* p = (char*)d_ws;
    auto carve = [&](size_t bytes) {
        char* r = p;
        p += (bytes + 255) & ~(size_t)255;
        return r;
    };
    float*  h    = (float*)carve((size_t)N_PAD * 64 * sizeof(float));
    ushort* xb   = (ushort*)carve((size_t)N_PAD * 64 * sizeof(short));
    ushort* xab  = (ushort*)carve((size_t)N_PAD * 64 * sizeof(short));
    ushort* eh   = (ushort*)carve((size_t)N_EDGES * 64 * sizeof(short));
    int* rp   = (int*)carve((size_t)(N_NODES + 1) * sizeof(int));
    int* nxt  = (int*)carve((size_t)N_NODES * sizeof(int));
    int* inc  = (int*)carve((size_t)N_NODES * sizeof(int));
    int* ssrc = (int*)carve((size_t)N_EDGES * sizeof(int));
    int* rank = (int*)carve((size_t)N_EDGES * sizeof(int));
    int* bsum = (int*)carve(512 * sizeof(int));
    int* boff = (int*)carve(512 * sizeof(int));
    short* W1T = (short*)carve((size_t)NLAYERS * 8192 * sizeof(short));
    short* W2T = (short*)carve((size_t)NLAYERS * 8192 * sizeof(short));
    short* WnT = (short*)carve((size_t)8192 * sizeof(short));
    short* WoT = (short*)carve((size_t)OUT_DIM * 64 * sizeof(short));

    // CSR by dst: one atomic pass (rank) + scan; positions computed in edge_enc
    hipMemsetAsync(nxt, 0, (size_t)N_NODES * sizeof(int), stream);
    k_rank<<<(N_EDGES / 4 + 255) / 256, 256, 0, stream>>>(dst, nxt, rank);
    k_scan_a<<<SCAN_BLOCKS, 256, 0, stream>>>(nxt, inc, bsum);
    k_scan_b<<<1, 512, 0, stream>>>(bsum, boff, SCAN_BLOCKS);
    k_scan_c<<<SCAN_BLOCKS, 256, 0, stream>>>(inc, boff, rp);

    // weight prep + encoders (node_enc fuses layer-0 LN/ReLU)
    k_prep_w<<<(NLAYERS * 8192 + 255) / 256, 256, 0, stream>>>(W1, W2, W_node, W_out,
                                                               W1T, W2T, WnT, WoT);
    k_node_enc_mfma<<<N_PAD / 64, 256, 0, stream>>>(node_feats, WnT, b_node, norm_g, norm_b, h, xb);
    k_edge_enc<<<(N_EDGES + 255) / 256, 256, 0, stream>>>(edge_feats, W_edge, b_edge,
                                                          dst, rank, rp, src, ssrc, eh);

    // layers; k_mlp_mfma epilogue produces xb for layer i+1 (final uses norm[0])
    for (int i = 0; i < NLAYERS; ++i) {
        int ni = (i + 1 < NLAYERS) ? (i + 1) : 0;
        k_agg<<<N_NODES / 8, 256, 0, stream>>>(xb, eh, ssrc, rp, betas, i, xab);
        k_mlp_mfma<<<N_PAD / 64, 256, 0, stream>>>(xab, W1T + i * 8192, b1 + i * 128,
                                                   ln1_g + i * 128, ln1_b + i * 128,
                                                   W2T + i * 8192, b2 + i * 64,
                                                   norm_g + ni * 64, norm_b + ni * 64,
                                                   h, xb);
    }

    // output linear (xb already = bf16(relu(LN_0(h))) from last mlp epilogue)
    k_out_mfma<<<N_PAD / 64, 256, 0, stream>>>(xb, WoT, b_out, out);
}